// Round 12
// baseline (78.366 us; speedup 1.0000x reference)
//
#include <hip/hip_runtime.h>
#include <hip/hip_bf16.h>

// ---------------------------------------------------------------------------
// Fused MLP+LSTM for B=131072 rows, v9 (2nd resubmit — infra failures x2):
// weight-stationary middle layers.
// 1024 blocks x 512 thr (8 waves), 128 rows/block, LDS 48KB -> 2 blocks/CU.
//  Phase L1  (row-parallel, t-split): wave = (m-pair p, t-half th). x from
//            global (own rows), FC1 frags from global ws. Writes h1 frags LDS.
//  Phase A/B (weight-stationary): wave owns output tile t; weight frags in
//            registers; activation frags streamed from LDS; writes b64 half-
//            frags back (lane-local repack). 2 barriers/layer.
//  Phase C   same, 4 t-tiles x 2 m-halves.
//  Tail      (row-parallel, v8-proven): wave=m reads h4 frags, L2..L5 + LSTM.
// Operand-swapped MFMA throughout: D = W*act^T, batch row at lane&15.
// ---------------------------------------------------------------------------

typedef __bf16 bf16x8 __attribute__((ext_vector_type(8)));
typedef __bf16 bf16x4 __attribute__((ext_vector_type(4)));
typedef float  f32x4  __attribute__((ext_vector_type(4)));

#define MFMA16(A, B, C) __builtin_amdgcn_mfma_f32_16x16x32_bf16((A), (B), (C), 0, 0, 0)

// ws fragment offsets (bf16 elems) — same prep layout as v8 (verified)
#define WOFF_FC1A_H 0
#define WOFF_FC1B   16384
#define WOFF_FC1C   32768
#define WOFF_FC1    40960
#define WOFF_FC1A_W 73728
#define WOFF_FC2    81920
#define WOFF_FC3    83968
#define WOFF_WIH    84992
#define WOFF_WHH    89088
#define WOFF_FC4    93184
#define WTOT        94208
#define BOFF_FC1  0
#define BOFF_FC1A 128
#define BOFF_FC1B 256
#define BOFF_FC1C 384
#define BOFF_FC2  448
#define BOFF_FC3  480
#define BOFF_LSTM 512
#define BOFF_FC4  640
#define BTOT      672

// LDS (bf16 elems): act frags [s2:4][m:8][lane:64][8] = 16384 elems (32KB),
// then w-operand frags [s2:2][m:8][lane:64][8] = 8192 elems (16KB).
#define ACT_ELEMS 16384
#define WLDS_BASE 16384
#define LDS_TOT   24576

__device__ __forceinline__ int actoff(int s2, int m, int lane) {
    return ((s2 * 8 + m) * 64 + lane) * 8;
}

// ---------------------------------------------------------------------------
// prep (unchanged from v8 — verified): fp32 -> bf16 frags + bias folding
// ---------------------------------------------------------------------------
__device__ __forceinline__ void conv_frag(int rel, const float* __restrict__ src,
                                          __bf16* __restrict__ dst,
                                          int ns, int Krow, int kbase, int klim, int perm) {
    int j    = rel & 7;
    int lane = (rel >> 3) & 63;
    int fs   = rel >> 9;
    int s    = fs % ns;
    int t    = fs / ns;
    int gq   = lane >> 4;
    int n    = 16 * t + (lane & 15);
    int k    = perm ? (16 * (2 * s + (j >> 2)) + 4 * gq + (j & 3))
                    : (32 * s + 8 * gq + j);
    float v  = (k < klim) ? src[n * Krow + kbase + k] : 0.f;
    dst[rel] = (__bf16)v;
}

__global__ void prep_kernel(const float* __restrict__ fc1w,  const float* __restrict__ fc1b,
                            const float* __restrict__ fc1aw, const float* __restrict__ fc1ab,
                            const float* __restrict__ fc1bw, const float* __restrict__ fc1bb,
                            const float* __restrict__ wgame, const float* __restrict__ fc1cw,
                            const float* __restrict__ fc1cb, const float* __restrict__ fc2w,
                            const float* __restrict__ fc2b,  const float* __restrict__ fc3w,
                            const float* __restrict__ fc3b,  const float* __restrict__ wih,
                            const float* __restrict__ whh,   const float* __restrict__ bih,
                            const float* __restrict__ bhh,   const float* __restrict__ fc4w,
                            const float* __restrict__ fc4b,
                            __bf16* __restrict__ wsw, float* __restrict__ wsb) {
    int idx = blockIdx.x * 256 + threadIdx.x;
    if (idx < WTOT) {
        if      (idx < WOFF_FC1B)   conv_frag(idx - WOFF_FC1A_H, fc1aw, wsw + WOFF_FC1A_H, 4, 164,   0, 128, 1);
        else if (idx < WOFF_FC1C)   conv_frag(idx - WOFF_FC1B,   fc1bw, wsw + WOFF_FC1B,   4, 128,   0, 128, 1);
        else if (idx < WOFF_FC1)    conv_frag(idx - WOFF_FC1C,   fc1cw, wsw + WOFF_FC1C,   4, 140,   0, 128, 1);
        else if (idx < WOFF_FC1A_W) conv_frag(idx - WOFF_FC1,    fc1w,  wsw + WOFF_FC1,    8, 256,   0, 256, 0);
        else if (idx < WOFF_FC2)    conv_frag(idx - WOFF_FC1A_W, fc1aw, wsw + WOFF_FC1A_W, 2, 164, 128,  36, 0);
        else if (idx < WOFF_FC3)    conv_frag(idx - WOFF_FC2,    fc2w,  wsw + WOFF_FC2,    2,  64,   0,  64, 1);
        else if (idx < WOFF_WIH)    conv_frag(idx - WOFF_FC3,    fc3w,  wsw + WOFF_FC3,    1,  32,   0,  32, 1);
        else if (idx < WOFF_WHH)    conv_frag(idx - WOFF_WIH,    wih,   wsw + WOFF_WIH,    1,  32,   0,  32, 1);
        else if (idx < WOFF_FC4)    conv_frag(idx - WOFF_WHH,    whh,   wsw + WOFF_WHH,    1,  32,   0,  32, 0);
        else                        conv_frag(idx - WOFF_FC4,    fc4w,  wsw + WOFF_FC4,    1,  32,   0,  32, 1);
    } else if (idx < WTOT + BTOT) {
        int bi = idx - WTOT;
        float v;
        if      (bi < 128) v = fc1b[bi];
        else if (bi < 256) v = fc1ab[bi - 128];
        else if (bi < 384) v = fc1bb[bi - 256];
        else if (bi < 448) {
            int n = bi - 384;
            v = fc1cb[n];
            for (int q = 0; q < 12; ++q) v += fc1cw[n * 140 + 128 + q] * wgame[q];
        }
        else if (bi < 480) v = fc2b[bi - 448];
        else if (bi < 512) v = fc3b[bi - 480];
        else if (bi < 640) { int n = bi - 512; v = bih[n] + bhh[n]; }
        else               v = fc4b[bi - 640];
        wsb[bi] = v;
    }
}

// ---------------------------------------------------------------------------
// Helpers
// ---------------------------------------------------------------------------
__device__ __forceinline__ bf16x8 ld8f(const float* __restrict__ p) {
    f32x4 a = *(const f32x4*)p;
    f32x4 b = *(const f32x4*)(p + 4);
    bf16x8 r;
    r[0] = (__bf16)a[0]; r[1] = (__bf16)a[1]; r[2] = (__bf16)a[2]; r[3] = (__bf16)a[3];
    r[4] = (__bf16)b[0]; r[5] = (__bf16)b[1]; r[6] = (__bf16)b[2]; r[7] = (__bf16)b[3];
    return r;
}

__device__ __forceinline__ bf16x8 ld4f_masked(const float* __restrict__ p, bool on) {
    f32x4 v = {0.f, 0.f, 0.f, 0.f};
    if (on) v = *(const f32x4*)p;
    bf16x8 r;
    r[0] = (__bf16)v[0]; r[1] = (__bf16)v[1]; r[2] = (__bf16)v[2]; r[3] = (__bf16)v[3];
    r[4] = (__bf16)0.f;  r[5] = (__bf16)0.f;  r[6] = (__bf16)0.f;  r[7] = (__bf16)0.f;
    return r;
}

// full-frag pack: elem j <- relu(a[2s+(j>>2)][j&3])   (a = 4 x f32x4)
__device__ __forceinline__ bf16x8 packrelu(const f32x4* a, int s) {
    bf16x8 r;
#pragma unroll
    for (int j = 0; j < 8; ++j) {
        float v = a[2 * s + (j >> 2)][j & 3];
        r[j] = (__bf16)fmaxf(v, 0.f);
    }
    return r;
}

// half-frag pack (weight-stationary wave owns one t): 4 x relu -> bf16x4
__device__ __forceinline__ bf16x4 pack4(f32x4 a) {
    bf16x4 r;
#pragma unroll
    for (int j = 0; j < 4; ++j) r[j] = (__bf16)fmaxf(a[j], 0.f);
    return r;
}

__device__ __forceinline__ float sigm(float v)  { return 1.f / (1.f + __expf(-v)); }
__device__ __forceinline__ float tanh_(float v) { return 1.f - 2.f / (1.f + __expf(2.f * v)); }

// ---------------------------------------------------------------------------
// Fused main kernel
// ---------------------------------------------------------------------------
__global__ __launch_bounds__(512, 4) void fused_mlp_lstm(
        const float* __restrict__ x,  const float* __restrict__ w,
        const float* __restrict__ h0, const float* __restrict__ c0,
        const float* __restrict__ fc5w, const float* __restrict__ fc5b,
        const __bf16* __restrict__ wsw, const float* __restrict__ wsb,
        float* __restrict__ out) {
    __shared__ __align__(16) __bf16 slds[LDS_TOT];   // 48 KB

    const int tid  = threadIdx.x;
    const int lane = tid & 63;
    const int wv   = tid >> 6;          // wave 0..7
    const int gq   = lane >> 4;
    const int mr   = lane & 15;
    const int blkrow = blockIdx.x * 128;

    // ---- stage w-operand frags (A_W) to LDS: 16 frags, 2 passes -----------
#pragma unroll
    for (int pass = 0; pass < 2; ++pass) {
        int fid  = pass * 8 + wv;          // = s2*8 + m
        int m    = fid & 7;
        int wrow = blkrow + 16 * m + mr;
        bf16x8 v = (pass == 0) ? ld8f(w + wrow * 36 + 8 * gq)
                               : ld4f_masked(w + wrow * 36 + 32, gq == 0);
        *(bf16x8*)(slds + WLDS_BASE + (fid * 64 + lane) * 8) = v;
    }

    // ---- Phase L1 (row-parallel, t-split): wave = (m-pair, t-half) --------
    {
        const int p  = wv & 3;             // m-pair -> m in {2p, 2p+1}
        const int th = wv >> 2;            // t in {4th .. 4th+3}
        const int row0 = blkrow + 32 * p + mr;
        const int row1 = row0 + 16;
        const bf16x8* Gfc1 = (const bf16x8*)(wsw + WOFF_FC1);

        f32x4 accA[4], accB[4];
#pragma unroll
        for (int tt = 0; tt < 4; ++tt) {
            f32x4 bv = *(const f32x4*)(wsb + BOFF_FC1 + 16 * (4 * th + tt) + 4 * gq);
            accA[tt] = bv; accB[tt] = bv;
        }
#pragma unroll
        for (int s = 0; s < 8; ++s) {
            bf16x8 xa = ld8f(x + row0 * 256 + 32 * s + 8 * gq);
            bf16x8 xb = ld8f(x + row1 * 256 + 32 * s + 8 * gq);
#pragma unroll
            for (int tt = 0; tt < 4; ++tt) {
                bf16x8 wf = Gfc1[((4 * th + tt) * 8 + s) * 64 + lane];
                accA[tt] = MFMA16(wf, xa, accA[tt]);
                accB[tt] = MFMA16(wf, xb, accB[tt]);
            }
        }
        // write h1 frags: full b128, frag (s2 = 2th+sh, m = 2p+mi)
#pragma unroll
        for (int sh = 0; sh < 2; ++sh) {
            *(bf16x8*)(slds + actoff(2 * th + sh, 2 * p + 0, lane)) = packrelu(accA, sh);
            *(bf16x8*)(slds + actoff(2 * th + sh, 2 * p + 1, lane)) = packrelu(accB, sh);
        }
    }
    __syncthreads();                                     // (1)

    // ---- Phase A (weight-stationary): h1(+w) -> h2, wave owns tile t=wv ---
    {
        const bf16x8* GA = (const bf16x8*)(wsw + WOFF_FC1A_H);
        const bf16x8* GW = (const bf16x8*)(wsw + WOFF_FC1A_W);
        bf16x8 WA[4], WW[2];
#pragma unroll
        for (int s = 0; s < 4; ++s) WA[s] = GA[(wv * 4 + s) * 64 + lane];
#pragma unroll
        for (int s = 0; s < 2; ++s) WW[s] = GW[(wv * 2 + s) * 64 + lane];

        f32x4 acc[8];
        f32x4 bv = *(const f32x4*)(wsb + BOFF_FC1A + 16 * wv + 4 * gq);
#pragma unroll
        for (int m = 0; m < 8; ++m) acc[m] = bv;
#pragma unroll
        for (int s = 0; s < 4; ++s)
#pragma unroll
            for (int m = 0; m < 8; ++m) {
                bf16x8 af = *(const bf16x8*)(slds + actoff(s, m, lane));
                acc[m] = MFMA16(WA[s], af, acc[m]);
            }
#pragma unroll
        for (int s2 = 0; s2 < 2; ++s2)
#pragma unroll
            for (int m = 0; m < 8; ++m) {
                bf16x8 af = *(const bf16x8*)(slds + WLDS_BASE + ((s2 * 8 + m) * 64 + lane) * 8);
                acc[m] = MFMA16(WW[s2], af, acc[m]);
            }
        __syncthreads();                                 // (2) all h1 reads done
        const int jh = wv & 1, s2o = wv >> 1;
#pragma unroll
        for (int m = 0; m < 8; ++m)
            *(bf16x4*)(slds + actoff(s2o, m, lane) + jh * 4) = pack4(acc[m]);
    }
    __syncthreads();                                     // (3)

    // ---- Phase B (weight-stationary): h2 -> h3 ----------------------------
    {
        const bf16x8* GB = (const bf16x8*)(wsw + WOFF_FC1B);
        bf16x8 WB[4];
#pragma unroll
        for (int s = 0; s < 4; ++s) WB[s] = GB[(wv * 4 + s) * 64 + lane];

        f32x4 acc[8];
        f32x4 bv = *(const f32x4*)(wsb + BOFF_FC1B + 16 * wv + 4 * gq);
#pragma unroll
        for (int m = 0; m < 8; ++m) acc[m] = bv;
#pragma unroll
        for (int s = 0; s < 4; ++s)
#pragma unroll
            for (int m = 0; m < 8; ++m) {
                bf16x8 af = *(const bf16x8*)(slds + actoff(s, m, lane));
                acc[m] = MFMA16(WB[s], af, acc[m]);
            }
        __syncthreads();                                 // (4)
        const int jh = wv & 1, s2o = wv >> 1;
#pragma unroll
        for (int m = 0; m < 8; ++m)
            *(bf16x4*)(slds + actoff(s2o, m, lane) + jh * 4) = pack4(acc[m]);
    }
    __syncthreads();                                     // (5)

    // ---- Phase C (weight-stationary): h3 -> h4 (64-wide, 4 tiles) ---------
    {
        const bf16x8* GC = (const bf16x8*)(wsw + WOFF_FC1C);
        const int tc = wv & 3, hh = wv >> 2;
        bf16x8 WC[4];
#pragma unroll
        for (int s = 0; s < 4; ++s) WC[s] = GC[(tc * 4 + s) * 64 + lane];

        f32x4 acc4[4];
        f32x4 bv = *(const f32x4*)(wsb + BOFF_FC1C + 16 * tc + 4 * gq);
#pragma unroll
        for (int mi = 0; mi < 4; ++mi) acc4[mi] = bv;
#pragma unroll
        for (int s = 0; s < 4; ++s)
#pragma unroll
            for (int mi = 0; mi < 4; ++mi) {
                bf16x8 af = *(const bf16x8*)(slds + actoff(s, 4 * hh + mi, lane));
                acc4[mi] = MFMA16(WC[s], af, acc4[mi]);
            }
        __syncthreads();                                 // (6)
        const int jh = tc & 1, s2o = tc >> 1;
#pragma unroll
        for (int mi = 0; mi < 4; ++mi)
            *(bf16x4*)(slds + actoff(s2o, 4 * hh + mi, lane) + jh * 4) = pack4(acc4[mi]);
    }
    __syncthreads();                                     // (7)

    // ---- Tail (row-parallel, wave = m): h4 -> out (v8-proven path) --------
    {
        const int rowbase = blkrow + 16 * wv;
        const int row     = rowbase + mr;
        const bf16x8* Wfc2 = (const bf16x8*)(wsw + WOFF_FC2);
        const bf16x8* Wfc3 = (const bf16x8*)(wsw + WOFF_FC3);
        const bf16x8* Wwih = (const bf16x8*)(wsw + WOFF_WIH);
        const bf16x8* Wwhh = (const bf16x8*)(wsw + WOFF_WHH);
        const bf16x8* Wfc4 = (const bf16x8*)(wsw + WOFF_FC4);

        bf16x8 h4f[2];
        h4f[0] = *(const bf16x8*)(slds + actoff(0, wv, lane));
        h4f[1] = *(const bf16x8*)(slds + actoff(1, wv, lane));

        // LSTM-state inputs issued early
        bf16x8 h0f  = ld8f(h0 + row * 32 + 8 * gq);
        f32x4  c0r0 = *(const f32x4*)(c0 + row * 32 + 4 * gq);
        f32x4  c0r1 = *(const f32x4*)(c0 + row * 32 + 16 + 4 * gq);

        // L2: h4[64] -> h5[32]
        bf16x8 h5f;
        {
            f32x4 acc5[2];
#pragma unroll
            for (int t = 0; t < 2; ++t)
                acc5[t] = *(const f32x4*)(wsb + BOFF_FC2 + 16 * t + 4 * gq);
#pragma unroll
            for (int s = 0; s < 2; ++s)
#pragma unroll
                for (int t = 0; t < 2; ++t)
                    acc5[t] = MFMA16(Wfc2[(t * 2 + s) * 64 + lane], h4f[s], acc5[t]);
            h5f = packrelu(acc5, 0);
        }
        // L3: h5[32] -> h6[32]
        bf16x8 h6f;
        {
            f32x4 acc6[2];
#pragma unroll
            for (int t = 0; t < 2; ++t)
                acc6[t] = *(const f32x4*)(wsb + BOFF_FC3 + 16 * t + 4 * gq);
#pragma unroll
            for (int t = 0; t < 2; ++t)
                acc6[t] = MFMA16(Wfc3[t * 64 + lane], h5f, acc6[t]);
            h6f = packrelu(acc6, 0);
        }
        // LSTM gates
        bf16x8 hnf;
        {
            f32x4 accg[8];
#pragma unroll
            for (int t = 0; t < 8; ++t)
                accg[t] = *(const f32x4*)(wsb + BOFF_LSTM + 16 * t + 4 * gq);
#pragma unroll
            for (int t = 0; t < 8; ++t)
                accg[t] = MFMA16(Wwih[t * 64 + lane], h6f, accg[t]);
#pragma unroll
            for (int t = 0; t < 8; ++t)
                accg[t] = MFMA16(Wwhh[t * 64 + lane], h0f, accg[t]);
#pragma unroll
            for (int t2 = 0; t2 < 2; ++t2) {
                f32x4 cc = t2 ? c0r1 : c0r0;
#pragma unroll
                for (int r = 0; r < 4; ++r) {
                    float ig = accg[t2][r];
                    float fg = accg[2 + t2][r];
                    float gg = accg[4 + t2][r];
                    float og = accg[6 + t2][r];
                    float cn = sigm(fg) * cc[r] + sigm(ig) * tanh_(gg);
                    hnf[t2 * 4 + r] = (__bf16)(sigm(og) * tanh_(cn));
                }
            }
        }
        // L4
        f32x4 acco[2];
#pragma unroll
        for (int t = 0; t < 2; ++t)
            acco[t] = *(const f32x4*)(wsb + BOFF_FC4 + 16 * t + 4 * gq);
#pragma unroll
        for (int t = 0; t < 2; ++t)
            acco[t] = MFMA16(Wfc4[t * 64 + lane], hnf, acco[t]);
        // L5 + sigmoid
        f32x4 w5a = *(const f32x4*)(fc5w + 4 * gq);
        f32x4 w5b = *(const f32x4*)(fc5w + 16 + 4 * gq);
        float p = 0.f;
#pragma unroll
        for (int r = 0; r < 4; ++r) {
            p += fmaxf(acco[0][r], 0.f) * w5a[r];
            p += fmaxf(acco[1][r], 0.f) * w5b[r];
        }
        p += __shfl_xor(p, 16);
        p += __shfl_xor(p, 32);
        float res = sigm(p + fc5b[0]);
        if (lane < 16) out[rowbase + lane] = res;
    }
}

// ---------------------------------------------------------------------------
extern "C" void kernel_launch(void* const* d_in, const int* in_sizes, int n_in,
                              void* d_out, int out_size, void* d_ws, size_t ws_size,
                              hipStream_t stream) {
    const float* x     = (const float*)d_in[0];
    const float* w     = (const float*)d_in[1];
    const float* h0    = (const float*)d_in[2];
    const float* c0    = (const float*)d_in[3];
    const float* fc1w  = (const float*)d_in[4];
    const float* fc1b  = (const float*)d_in[5];
    const float* fc1aw = (const float*)d_in[6];
    const float* fc1ab = (const float*)d_in[7];
    const float* fc1bw = (const float*)d_in[8];
    const float* fc1bb = (const float*)d_in[9];
    const float* wgame = (const float*)d_in[10];
    const float* fc1cw = (const float*)d_in[11];
    const float* fc1cb = (const float*)d_in[12];
    const float* fc2w  = (const float*)d_in[13];
    const float* fc2b  = (const float*)d_in[14];
    const float* fc3w  = (const float*)d_in[15];
    const float* fc3b  = (const float*)d_in[16];
    const float* wih   = (const float*)d_in[17];
    const float* whh   = (const float*)d_in[18];
    const float* bih   = (const float*)d_in[19];
    const float* bhh   = (const float*)d_in[20];
    const float* fc4w  = (const float*)d_in[21];
    const float* fc4b  = (const float*)d_in[22];
    const float* fc5w  = (const float*)d_in[23];
    const float* fc5b  = (const float*)d_in[24];

    __bf16* wsw = (__bf16*)d_ws;
    float*  wsb = (float*)((char*)d_ws + WTOT * sizeof(__bf16));
    (void)ws_size; (void)n_in; (void)out_size;

    const int Btot = in_sizes[0] / 256;   // 131072 rows

    prep_kernel<<<(WTOT + BTOT + 255) / 256, 256, 0, stream>>>(
        fc1w, fc1b, fc1aw, fc1ab, fc1bw, fc1bb, wgame, fc1cw, fc1cb,
        fc2w, fc2b, fc3w, fc3b, wih, whh, bih, bhh, fc4w, fc4b, wsw, wsb);

    fused_mlp_lstm<<<Btot / 128, 512, 0, stream>>>(
        x, w, h0, c0, fc5w, fc5b, wsw, wsb, (float*)d_out);
}

// Round 13
// 75.881 us; speedup vs baseline: 1.0327x; 1.0327x over previous
//
#include <hip/hip_runtime.h>
#include <hip/hip_bf16.h>

// ---------------------------------------------------------------------------
// Fused MLP+LSTM for B=131072 rows, v10.
// 768-thread blocks (12 waves, 3 waves/SIMD via __launch_bounds__(768,3) ->
// ~168-reg cap, fits M=1 without spill). 144 KB LDS holds ALL four fat
// weight layers. All per-row global inputs (x, w, h0, c0) are issued BEFORE
// the staging barrier so the post-barrier chain reads only LDS + L2-hot
// small-layer frags. Grid = ceil(B/192) with guarded tail.
// Operand-swapped MFMA chain: D = W*act^T keeps batch row at lane&15.
// ---------------------------------------------------------------------------

typedef __bf16 bf16x8 __attribute__((ext_vector_type(8)));
typedef float  f32x4  __attribute__((ext_vector_type(4)));
typedef int    i32x4  __attribute__((ext_vector_type(4)));

#define MFMA16(A, B, C) __builtin_amdgcn_mfma_f32_16x16x32_bf16((A), (B), (C), 0, 0, 0)

// fragment-element offsets (bf16 elems). [0, LDS_ELEMS) staged to LDS.
#define WOFF_FC1    0
#define WOFF_FC1A_H 32768
#define WOFF_FC1B   49152
#define WOFF_FC1C   65536
#define LDS_ELEMS   73728          // 147456 B = 144 KB
#define WOFF_FC1A_W 73728
#define WOFF_FC2    81920
#define WOFF_FC3    83968
#define WOFF_WIH    84992
#define WOFF_WHH    89088
#define WOFF_FC4    93184
#define WTOT        94208
// bias offsets (floats, after bf16 region in ws)
#define BOFF_FC1  0
#define BOFF_FC1A 128
#define BOFF_FC1B 256
#define BOFF_FC1C 384
#define BOFF_FC2  448
#define BOFF_FC3  480
#define BOFF_LSTM 512
#define BOFF_FC4  640
#define BTOT      672

// ---------------------------------------------------------------------------
// Fragment mapping (verified since v1):
//   rel -> j = rel&7, lane = (rel>>3)&63, fs = rel>>9, s = fs%ns, t = fs/ns,
//   gq = lane>>4, n = 16t + (lane&15),
//   k = perm ? 16*(2s + (j>>2)) + 4*gq + (j&3) : 32*s + 8*gq + j
// ---------------------------------------------------------------------------
__device__ __forceinline__ void conv_frag(int rel, const float* __restrict__ src,
                                          __bf16* __restrict__ dst,
                                          int ns, int Krow, int kbase, int klim, int perm) {
    int j    = rel & 7;
    int lane = (rel >> 3) & 63;
    int fs   = rel >> 9;
    int s    = fs % ns;
    int t    = fs / ns;
    int gq   = lane >> 4;
    int n    = 16 * t + (lane & 15);
    int k    = perm ? (16 * (2 * s + (j >> 2)) + 4 * gq + (j & 3))
                    : (32 * s + 8 * gq + j);
    float v  = (k < klim) ? src[n * Krow + kbase + k] : 0.f;
    dst[rel] = (__bf16)v;
}

// ---------------------------------------------------------------------------
// Prep: full fp32 -> bf16 fragment conversion + bias folding (runs once).
// ---------------------------------------------------------------------------
__global__ void prep_kernel(const float* __restrict__ fc1w,  const float* __restrict__ fc1b,
                            const float* __restrict__ fc1aw, const float* __restrict__ fc1ab,
                            const float* __restrict__ fc1bw, const float* __restrict__ fc1bb,
                            const float* __restrict__ wgame, const float* __restrict__ fc1cw,
                            const float* __restrict__ fc1cb, const float* __restrict__ fc2w,
                            const float* __restrict__ fc2b,  const float* __restrict__ fc3w,
                            const float* __restrict__ fc3b,  const float* __restrict__ wih,
                            const float* __restrict__ whh,   const float* __restrict__ bih,
                            const float* __restrict__ bhh,   const float* __restrict__ fc4w,
                            const float* __restrict__ fc4b,
                            __bf16* __restrict__ wsw, float* __restrict__ wsb) {
    int idx = blockIdx.x * 256 + threadIdx.x;
    if (idx < WTOT) {
        if      (idx < WOFF_FC1A_H) conv_frag(idx - WOFF_FC1,    fc1w,  wsw + WOFF_FC1,    8, 256,   0, 256, 0);
        else if (idx < WOFF_FC1B)   conv_frag(idx - WOFF_FC1A_H, fc1aw, wsw + WOFF_FC1A_H, 4, 164,   0, 128, 1);
        else if (idx < WOFF_FC1C)   conv_frag(idx - WOFF_FC1B,   fc1bw, wsw + WOFF_FC1B,   4, 128,   0, 128, 1);
        else if (idx < WOFF_FC1A_W) conv_frag(idx - WOFF_FC1C,   fc1cw, wsw + WOFF_FC1C,   4, 140,   0, 128, 1);
        else if (idx < WOFF_FC2)    conv_frag(idx - WOFF_FC1A_W, fc1aw, wsw + WOFF_FC1A_W, 2, 164, 128,  36, 0);
        else if (idx < WOFF_FC3)    conv_frag(idx - WOFF_FC2,    fc2w,  wsw + WOFF_FC2,    2,  64,   0,  64, 1);
        else if (idx < WOFF_WIH)    conv_frag(idx - WOFF_FC3,    fc3w,  wsw + WOFF_FC3,    1,  32,   0,  32, 1);
        else if (idx < WOFF_WHH)    conv_frag(idx - WOFF_WIH,    wih,   wsw + WOFF_WIH,    1,  32,   0,  32, 1);
        else if (idx < WOFF_FC4)    conv_frag(idx - WOFF_WHH,    whh,   wsw + WOFF_WHH,    1,  32,   0,  32, 0);
        else                        conv_frag(idx - WOFF_FC4,    fc4w,  wsw + WOFF_FC4,    1,  32,   0,  32, 1);
    } else if (idx < WTOT + BTOT) {
        int bi = idx - WTOT;
        float v;
        if      (bi < 128) v = fc1b[bi];
        else if (bi < 256) v = fc1ab[bi - 128];
        else if (bi < 384) v = fc1bb[bi - 256];
        else if (bi < 448) {            // fold fc1c_w[:,128:140] @ w_game into bias
            int n = bi - 384;
            v = fc1cb[n];
            for (int q = 0; q < 12; ++q) v += fc1cw[n * 140 + 128 + q] * wgame[q];
        }
        else if (bi < 480) v = fc2b[bi - 448];
        else if (bi < 512) v = fc3b[bi - 480];
        else if (bi < 640) { int n = bi - 512; v = bih[n] + bhh[n]; }   // fused LSTM bias
        else               v = fc4b[bi - 640];
        wsb[bi] = v;
    }
}

// ---------------------------------------------------------------------------
// Helpers
// ---------------------------------------------------------------------------
__device__ __forceinline__ bf16x8 ld8f(const float* __restrict__ p) {
    f32x4 a = *(const f32x4*)p;
    f32x4 b = *(const f32x4*)(p + 4);
    bf16x8 r;
    r[0] = (__bf16)a[0]; r[1] = (__bf16)a[1]; r[2] = (__bf16)a[2]; r[3] = (__bf16)a[3];
    r[4] = (__bf16)b[0]; r[5] = (__bf16)b[1]; r[6] = (__bf16)b[2]; r[7] = (__bf16)b[3];
    return r;
}

__device__ __forceinline__ bf16x8 ld4f_masked(const float* __restrict__ p, bool on) {
    f32x4 v = {0.f, 0.f, 0.f, 0.f};
    if (on) v = *(const f32x4*)p;
    bf16x8 r;
    r[0] = (__bf16)v[0]; r[1] = (__bf16)v[1]; r[2] = (__bf16)v[2]; r[3] = (__bf16)v[3];
    r[4] = (__bf16)0.f;  r[5] = (__bf16)0.f;  r[6] = (__bf16)0.f;  r[7] = (__bf16)0.f;
    return r;
}

// pack acc[2s],acc[2s+1] (n = 16t+4g+r) into next-layer B-frag, with relu
__device__ __forceinline__ bf16x8 packrelu(const f32x4* a, int s) {
    bf16x8 r;
#pragma unroll
    for (int j = 0; j < 8; ++j) {
        float v = a[2 * s + (j >> 2)][j & 3];
        r[j] = (__bf16)fmaxf(v, 0.f);
    }
    return r;
}

__device__ __forceinline__ float sigm(float v)  { return 1.f / (1.f + __expf(-v)); }
__device__ __forceinline__ float tanh_(float v) { return 1.f - 2.f / (1.f + __expf(2.f * v)); }

// ---------------------------------------------------------------------------
// Fused main kernel: 12 waves/block, 16 rows/wave, 192 rows/block
// ---------------------------------------------------------------------------
__global__ __launch_bounds__(768, 3) void fused_mlp_lstm(
        const float* __restrict__ x,  const float* __restrict__ w,
        const float* __restrict__ h0, const float* __restrict__ c0,
        const float* __restrict__ fc5w, const float* __restrict__ fc5b,
        const __bf16* __restrict__ wsw, const float* __restrict__ wsb,
        float* __restrict__ out, int Btot) {
    __shared__ __align__(16) __bf16 slds[LDS_ELEMS];   // 144 KB

    const int tid     = threadIdx.x;
    const int lane    = tid & 63;
    const int wv      = tid >> 6;                      // 0..11
    const int gq      = lane >> 4;
    const int mr      = lane & 15;
    const int rowbase = blockIdx.x * 192 + wv * 16;
    int row = rowbase + mr;
    if (row > Btot - 1) row = Btot - 1;                // clamp tail reads

    // ---- issue ALL per-row global inputs (in flight during staging) -------
    bf16x8 xf[8];
#pragma unroll
    for (int s = 0; s < 8; ++s) xf[s] = ld8f(x + row * 256 + 32 * s + 8 * gq);
    bf16x8 wxa0 = ld8f(w + row * 36 + 8 * gq);
    bf16x8 wxa1 = ld4f_masked(w + row * 36 + 32, gq == 0);
    bf16x8 h0f  = ld8f(h0 + row * 32 + 8 * gq);
    f32x4  c0r0 = *(const f32x4*)(c0 + row * 32 + 4 * gq);
    f32x4  c0r1 = *(const f32x4*)(c0 + row * 32 + 16 + 4 * gq);

    // ---- stage all big weight layers to LDS (12 x 16B per thread) ---------
    {
        const i32x4* gs = (const i32x4*)wsw;
        i32x4*       sd = (i32x4*)slds;
#pragma unroll
        for (int i = 0; i < 12; ++i) sd[i * 768 + tid] = gs[i * 768 + tid];
    }
    __syncthreads();

    const bf16x8* Wfc1  = (const bf16x8*)(slds + WOFF_FC1);
    const bf16x8* Wf1aH = (const bf16x8*)(slds + WOFF_FC1A_H);
    const bf16x8* Wfc1b = (const bf16x8*)(slds + WOFF_FC1B);
    const bf16x8* Wfc1c = (const bf16x8*)(slds + WOFF_FC1C);
    const bf16x8* Wf1aW = (const bf16x8*)(wsw + WOFF_FC1A_W);
    const bf16x8* Wfc2  = (const bf16x8*)(wsw + WOFF_FC2);
    const bf16x8* Wfc3  = (const bf16x8*)(wsw + WOFF_FC3);
    const bf16x8* Wwih  = (const bf16x8*)(wsw + WOFF_WIH);
    const bf16x8* Wwhh  = (const bf16x8*)(wsw + WOFF_WHH);
    const bf16x8* Wfc4  = (const bf16x8*)(wsw + WOFF_FC4);

    // ---- L1: x[256] -> h1[128] -------------------------------------------
    bf16x8 h1f[4];
    {
        f32x4 acc1[8];
#pragma unroll
        for (int t = 0; t < 8; ++t)
            acc1[t] = *(const f32x4*)(wsb + BOFF_FC1 + 16 * t + 4 * gq);
#pragma unroll
        for (int s = 0; s < 8; ++s)
#pragma unroll
            for (int t = 0; t < 8; ++t)
                acc1[t] = MFMA16(Wfc1[(t * 8 + s) * 64 + lane], xf[s], acc1[t]);
#pragma unroll
        for (int s = 0; s < 4; ++s) h1f[s] = packrelu(acc1, s);
    }

    // ---- L1a: [h1, w] (128+36) -> h2[128] --------------------------------
    bf16x8 h2f[4];
    {
        f32x4 acc2[8];
#pragma unroll
        for (int t = 0; t < 8; ++t)
            acc2[t] = *(const f32x4*)(wsb + BOFF_FC1A + 16 * t + 4 * gq);
#pragma unroll
        for (int s = 0; s < 4; ++s)
#pragma unroll
            for (int t = 0; t < 8; ++t)
                acc2[t] = MFMA16(Wf1aH[(t * 4 + s) * 64 + lane], h1f[s], acc2[t]);
#pragma unroll
        for (int t = 0; t < 8; ++t) {
            acc2[t] = MFMA16(Wf1aW[(t * 2 + 0) * 64 + lane], wxa0, acc2[t]);
            acc2[t] = MFMA16(Wf1aW[(t * 2 + 1) * 64 + lane], wxa1, acc2[t]);
        }
#pragma unroll
        for (int s = 0; s < 4; ++s) h2f[s] = packrelu(acc2, s);
    }

    // ---- L1b: h2[128] -> h3[128] -----------------------------------------
    bf16x8 h3f[4];
    {
        f32x4 acc3[8];
#pragma unroll
        for (int t = 0; t < 8; ++t)
            acc3[t] = *(const f32x4*)(wsb + BOFF_FC1B + 16 * t + 4 * gq);
#pragma unroll
        for (int s = 0; s < 4; ++s)
#pragma unroll
            for (int t = 0; t < 8; ++t)
                acc3[t] = MFMA16(Wfc1b[(t * 4 + s) * 64 + lane], h2f[s], acc3[t]);
#pragma unroll
        for (int s = 0; s < 4; ++s) h3f[s] = packrelu(acc3, s);
    }

    // ---- L1c: [h3, w_game] -> h4[64]  (w_game folded into bias) ----------
    bf16x8 h4f[2];
    {
        f32x4 acc4[4];
#pragma unroll
        for (int t = 0; t < 4; ++t)
            acc4[t] = *(const f32x4*)(wsb + BOFF_FC1C + 16 * t + 4 * gq);
#pragma unroll
        for (int s = 0; s < 4; ++s)
#pragma unroll
            for (int t = 0; t < 4; ++t)
                acc4[t] = MFMA16(Wfc1c[(t * 4 + s) * 64 + lane], h3f[s], acc4[t]);
#pragma unroll
        for (int s = 0; s < 2; ++s) h4f[s] = packrelu(acc4, s);
    }

    // ---- L2: h4[64] -> h5[32] --------------------------------------------
    bf16x8 h5f;
    {
        f32x4 acc5[2];
#pragma unroll
        for (int t = 0; t < 2; ++t)
            acc5[t] = *(const f32x4*)(wsb + BOFF_FC2 + 16 * t + 4 * gq);
#pragma unroll
        for (int s = 0; s < 2; ++s)
#pragma unroll
            for (int t = 0; t < 2; ++t)
                acc5[t] = MFMA16(Wfc2[(t * 2 + s) * 64 + lane], h4f[s], acc5[t]);
        h5f = packrelu(acc5, 0);
    }

    // ---- L3: h5[32] -> h6[32] --------------------------------------------
    bf16x8 h6f;
    {
        f32x4 acc6[2];
#pragma unroll
        for (int t = 0; t < 2; ++t)
            acc6[t] = *(const f32x4*)(wsb + BOFF_FC3 + 16 * t + 4 * gq);
#pragma unroll
        for (int t = 0; t < 2; ++t)
            acc6[t] = MFMA16(Wfc3[t * 64 + lane], h5f, acc6[t]);
        h6f = packrelu(acc6, 0);
    }

    // ---- LSTM gates ------------------------------------------------------
    bf16x8 hnf;
    {
        f32x4 accg[8];
#pragma unroll
        for (int t = 0; t < 8; ++t)
            accg[t] = *(const f32x4*)(wsb + BOFF_LSTM + 16 * t + 4 * gq);
#pragma unroll
        for (int t = 0; t < 8; ++t)
            accg[t] = MFMA16(Wwih[t * 64 + lane], h6f, accg[t]);
#pragma unroll
        for (int t = 0; t < 8; ++t)
            accg[t] = MFMA16(Wwhh[t * 64 + lane], h0f, accg[t]);
        // gate tiles: i -> {0,1}, f -> {2,3}, g -> {4,5}, o -> {6,7}
#pragma unroll
        for (int t2 = 0; t2 < 2; ++t2) {
            f32x4 cc = t2 ? c0r1 : c0r0;
#pragma unroll
            for (int r = 0; r < 4; ++r) {
                float ig = accg[t2][r];
                float fg = accg[2 + t2][r];
                float gg = accg[4 + t2][r];
                float og = accg[6 + t2][r];
                float cn = sigm(fg) * cc[r] + sigm(ig) * tanh_(gg);
                hnf[t2 * 4 + r] = (__bf16)(sigm(og) * tanh_(cn));
            }
        }
    }

    // ---- L4: h_new[32] -> o1[32] -----------------------------------------
    f32x4 acco[2];
#pragma unroll
    for (int t = 0; t < 2; ++t)
        acco[t] = *(const f32x4*)(wsb + BOFF_FC4 + 16 * t + 4 * gq);
#pragma unroll
    for (int t = 0; t < 2; ++t)
        acco[t] = MFMA16(Wfc4[t * 64 + lane], hnf, acco[t]);

    // ---- L5 + sigmoid ----------------------------------------------------
    f32x4 w5a = *(const f32x4*)(fc5w + 4 * gq);
    f32x4 w5b = *(const f32x4*)(fc5w + 16 + 4 * gq);
    float p = 0.f;
#pragma unroll
    for (int r = 0; r < 4; ++r) {
        p += fmaxf(acco[0][r], 0.f) * w5a[r];
        p += fmaxf(acco[1][r], 0.f) * w5b[r];
    }
    p += __shfl_xor(p, 16);
    p += __shfl_xor(p, 32);
    float res = sigm(p + fc5b[0]);
    if (lane < 16) {
        int orow = rowbase + lane;
        if (orow < Btot) out[orow] = res;
    }
}

// ---------------------------------------------------------------------------
extern "C" void kernel_launch(void* const* d_in, const int* in_sizes, int n_in,
                              void* d_out, int out_size, void* d_ws, size_t ws_size,
                              hipStream_t stream) {
    const float* x     = (const float*)d_in[0];
    const float* w     = (const float*)d_in[1];
    const float* h0    = (const float*)d_in[2];
    const float* c0    = (const float*)d_in[3];
    const float* fc1w  = (const float*)d_in[4];
    const float* fc1b  = (const float*)d_in[5];
    const float* fc1aw = (const float*)d_in[6];
    const float* fc1ab = (const float*)d_in[7];
    const float* fc1bw = (const float*)d_in[8];
    const float* fc1bb = (const float*)d_in[9];
    const float* wgame = (const float*)d_in[10];
    const float* fc1cw = (const float*)d_in[11];
    const float* fc1cb = (const float*)d_in[12];
    const float* fc2w  = (const float*)d_in[13];
    const float* fc2b  = (const float*)d_in[14];
    const float* fc3w  = (const float*)d_in[15];
    const float* fc3b  = (const float*)d_in[16];
    const float* wih   = (const float*)d_in[17];
    const float* whh   = (const float*)d_in[18];
    const float* bih   = (const float*)d_in[19];
    const float* bhh   = (const float*)d_in[20];
    const float* fc4w  = (const float*)d_in[21];
    const float* fc4b  = (const float*)d_in[22];
    const float* fc5w  = (const float*)d_in[23];
    const float* fc5b  = (const float*)d_in[24];

    __bf16* wsw = (__bf16*)d_ws;
    float*  wsb = (float*)((char*)d_ws + WTOT * sizeof(__bf16));
    (void)ws_size; (void)n_in; (void)out_size;

    const int Btot = in_sizes[0] / 256;   // 131072 rows

    prep_kernel<<<(WTOT + BTOT + 255) / 256, 256, 0, stream>>>(
        fc1w, fc1b, fc1aw, fc1ab, fc1bw, fc1bb, wgame, fc1cw, fc1cb,
        fc2w, fc2b, fc3w, fc3b, wih, whh, bih, bhh, fc4w, fc4b, wsw, wsb);

    fused_mlp_lstm<<<(Btot + 191) / 192, 768, 0, stream>>>(
        x, w, h0, c0, fc5w, fc5b, wsw, wsb, (float*)d_out, Btot);
}